// Round 15
// baseline (443.975 us; speedup 1.0000x reference)
//
#include <hip/hip_runtime.h>
#include <stdint.h>

// ---------- problem constants (hardcoded from reference) ----------
// B=4, Q_LENS={256,512,128,384}, HIST={1792,1024,1536,768}
// Q_START={0,256,768,896}, KV_LENS={2048,1536,1664,1152}
// H=32, D=128, HID=4096, BS=64, MAX_KV=2048, MAX_BLOCKS=32, TOTAL_Q=1280

typedef __attribute__((ext_vector_type(8))) short bf16x8;
typedef __attribute__((ext_vector_type(4))) float f32x4;
typedef __attribute__((ext_vector_type(4))) unsigned int u32x4;

__device__ __forceinline__ unsigned short f2bf(float f) {
  unsigned int u = __float_as_uint(f);
  u += 0x7fffu + ((u >> 16) & 1u);
  return (unsigned short)(u >> 16);
}
__device__ __forceinline__ float bf2f(unsigned short u) {
  return __uint_as_float(((unsigned int)u) << 16);
}
__device__ __forceinline__ unsigned short f2h(float f) {
  _Float16 h = (_Float16)f;
  return __builtin_bit_cast(unsigned short, h);
}
__device__ __forceinline__ float h2f(unsigned short u) {
  return (float)__builtin_bit_cast(_Float16, u);
}

// ---------- fused pass 1: history gather (blocks 0..2559) + grid-stride cvt ----------
// Gather first so its scattered-latency blocks overlap the streaming cvt blocks
// instead of forming a tail. Cvt: 4096 blocks grid-stride, 2 float4/thread/iter
// (32B read + one 16B store) per G11/G13.
__global__ __launch_bounds__(256) void cvt_gather(const float* __restrict__ wq,
                                                  const float* __restrict__ wk,
                                                  const float* __restrict__ wv,
                                                  const float* __restrict__ wo,
                                                  const float* __restrict__ hs,
                                                  unsigned short* __restrict__ dst,
                                                  const float* __restrict__ pk,
                                                  const float* __restrict__ pv,
                                                  const int* __restrict__ btab,
                                                  unsigned short* __restrict__ Kg,
                                                  unsigned short* __restrict__ VgT) {
  if (blockIdx.x >= 2560) {
    // ---- grid-stride fp32->bf16 convert (pairs of float4) ----
    const long npairs = 9043968;  // 18087936 float4 / 2
    const long stride = (long)4096 * 256;
    for (long j = (long)(blockIdx.x - 2560) * 256 + threadIdx.x; j < npairs; j += stride) {
      long i = 2 * j;
      const float* src;
      long off;
      if (i < 4194304)        { src = wq; off = i; }
      else if (i < 8388608)   { src = wk; off = i - 4194304; }
      else if (i < 12582912)  { src = wv; off = i - 8388608; }
      else if (i < 16777216)  { src = wo; off = i - 12582912; }
      else                    { src = hs; off = i - 16777216; }
      float4 v0 = ((const float4*)src)[off];
      float4 v1 = ((const float4*)src)[off + 1];
      ushort4 o0, o1;
      o0.x = f2bf(v0.x); o0.y = f2bf(v0.y); o0.z = f2bf(v0.z); o0.w = f2bf(v0.w);
      o1.x = f2bf(v1.x); o1.y = f2bf(v1.y); o1.z = f2bf(v1.z); o1.w = f2bf(v1.w);
      u32x4 pk4;
      pk4[0] = (unsigned)o0.x | ((unsigned)o0.y << 16);
      pk4[1] = (unsigned)o0.z | ((unsigned)o0.w << 16);
      pk4[2] = (unsigned)o1.x | ((unsigned)o1.y << 16);
      pk4[3] = (unsigned)o1.z | ((unsigned)o1.w << 16);
      *(u32x4*)(dst + 4 * i) = pk4;
    }
    return;
  }
  // ---- gather history K,V (blocks 0..2559) ----
  int gid = blockIdx.x;
  int gx = gid % 80, h = gid / 80;
  int b = (gx < 28) ? 0 : (gx < 44) ? 1 : (gx < 68) ? 2 : 3;
  int jt = gx - ((b == 0) ? 0 : (b == 1) ? 28 : (b == 2) ? 44 : 68);
  int slot0 = btab[b * 32 + jt] * 64;
  int jbase = jt * 64;
  __shared__ unsigned short vt[64][130];
  int tid = threadIdx.x;
  int jj0 = tid >> 5, c4 = (tid & 31) * 4;
#pragma unroll
  for (int ps = 0; ps < 8; ++ps) {
    int jj = jj0 + ps * 8;
    long off = ((long)(slot0 + jj) * 32 + h) * 128 + c4;
    float4 kk = *(const float4*)(pk + off);
    ushort4 ko;
    ko.x = f2bf(kk.x); ko.y = f2bf(kk.y); ko.z = f2bf(kk.z); ko.w = f2bf(kk.w);
    *(ushort4*)(Kg + ((long)(b * 32 + h) * 2048 + jbase + jj) * 128 + c4) = ko;
    float4 vv = *(const float4*)(pv + off);
    ushort2 a, c;
    a.x = f2bf(vv.x); a.y = f2bf(vv.y); c.x = f2bf(vv.z); c.y = f2bf(vv.w);
    *(ushort2*)&vt[jj][c4] = a;
    *(ushort2*)&vt[jj][c4 + 2] = c;
  }
  __syncthreads();
  int d = tid >> 1, half = tid & 1;
  unsigned short* dstv = VgT + ((long)(b * 32 + h) * 128 + d) * 2048 + jbase + half * 32;
  int j0 = half * 32;
#pragma unroll
  for (int w = 0; w < 4; ++w) {
    uint4 u;
    u.x = vt[j0 + w * 8 + 0][d] | ((unsigned)vt[j0 + w * 8 + 1][d] << 16);
    u.y = vt[j0 + w * 8 + 2][d] | ((unsigned)vt[j0 + w * 8 + 3][d] << 16);
    u.z = vt[j0 + w * 8 + 4][d] | ((unsigned)vt[j0 + w * 8 + 5][d] << 16);
    u.w = vt[j0 + w * 8 + 6][d] | ((unsigned)vt[j0 + w * 8 + 7][d] << 16);
    ((uint4*)dstv)[w] = u;
  }
}

__device__ __forceinline__ void gload16(const void* g, void* l) {
  __builtin_amdgcn_global_load_lds(
      (const __attribute__((address_space(1))) unsigned int*)(g),
      (__attribute__((address_space(3))) unsigned int*)(l), 16, 0, 0);
}

#define MFMA_BF16(a, b, c) __builtin_amdgcn_mfma_f32_16x16x32_bf16((a), (b), (c), 0, 0, 0)

// ---------- 256x256 8-phase bf16 GEMM (frozen R13: counted lgkm cascades, bf16 out) ----------
__global__ __launch_bounds__(512, 2) void gemm256(const unsigned short* __restrict__ A,
                                                  const unsigned short* __restrict__ B,
                                                  unsigned short* __restrict__ C, int N, int K) {
  extern __shared__ char lds[];  // 131072
  const int tid = threadIdx.x;
  const int lane = tid & 63;
  const int wid = tid >> 6;
  const int wm = wid >> 2, wn = wid & 3;
  const int qcol = lane & 15, g = lane >> 4;
  const int mbase = blockIdx.y * 256, nbase = blockIdx.x * 256;
  const long Kb = (long)K * 2;
  const int ktmax = (K >> 6) - 1;  // 63

  const char* Ab = (const char*)A;
  const char* Bb = (const char*)B;
  const int srow = tid >> 3;
  const int ssw = ((tid & 7) ^ (srow & 7)) * 16;  // pre-swizzled 16B source slot

#define STG_HT(MB, GB, HF, BUF, KT) {                                          \
    long ro = (long)((GB) + (HF) * 128 + srow) * Kb + (long)(KT) * 128 + ssw;  \
    char* d = lds + (BUF) * 65536 + (MB) * 32768 + (HF) * 16384 + tid * 16;    \
    const char* sp = (MB) ? Bb : Ab;                                           \
    gload16(sp + ro, d);                                                       \
    gload16(sp + ro + 64 * Kb, d + 8192);                                      \
  }

  const int aoffB = wm * 16384 + qcol * 128;                               // + mi*2048 + swk
  const int boffB = 32768 + (wn >> 1) * 16384 + ((wn & 1) * 64 + qcol) * 128;  // + ni*2048 + swk
  const int swk0 = ((g) ^ (qcol & 7)) * 16;
  const int swk1 = ((4 + g) ^ (qcol & 7)) * 16;

  f32x4 acc[8][4];
#pragma unroll
  for (int i = 0; i < 8; ++i)
#pragma unroll
    for (int j = 0; j < 4; ++j) { acc[i][j][0]=0.f; acc[i][j][1]=0.f; acc[i][j][2]=0.f; acc[i][j][3]=0.f; }

#define SB()      __builtin_amdgcn_sched_barrier(0)
#define BARRIER() { __builtin_amdgcn_sched_barrier(0); __builtin_amdgcn_s_barrier(); }
#define LG6()     { asm volatile("s_waitcnt lgkmcnt(6)" ::: "memory"); SB(); }
#define LG4()     { asm volatile("s_waitcnt lgkmcnt(4)" ::: "memory"); SB(); }
#define LG2()     { asm volatile("s_waitcnt lgkmcnt(2)" ::: "memory"); SB(); }
#define LG0()     { asm volatile("s_waitcnt lgkmcnt(0)" ::: "memory"); SB(); }
#define VM4()     { asm volatile("s_waitcnt vmcnt(4)" ::: "memory"); SB(); }
#define RD(p)     (*(const bf16x8*)(p))

  STG_HT(0, mbase, 0, 0, 0); STG_HT(0, mbase, 1, 0, 0);
  STG_HT(1, nbase, 0, 0, 0); STG_HT(1, nbase, 1, 0, 0);
  STG_HT(1, nbase, 0, 1, 1); STG_HT(1, nbase, 1, 1, 1);
  VM4();
  __builtin_amdgcn_s_barrier();

#define PH_AB(L)                                                                \
    af[0][0] = RD(L + aoffB + swk0);        af[0][1] = RD(L + aoffB + swk1);    \
    SB();                                                                       \
    bfv[0][0] = RD(L + boffB + swk0);       bfv[0][1] = RD(L + boffB + swk1);   \
    bfv[1][0] = RD(L + boffB + 2048 + swk0); bfv[1][1] = RD(L + boffB + 2048 + swk1); \
    SB();                                                                       \
    af[1][0] = RD(L + aoffB + 2048 + swk0); af[1][1] = RD(L + aoffB + 2048 + swk1); \
    SB();                                                                       \
    af[2][0] = RD(L + aoffB + 4096 + swk0); af[2][1] = RD(L + aoffB + 4096 + swk1); \
    SB();                                                                       \
    af[3][0] = RD(L + aoffB + 6144 + swk0); af[3][1] = RD(L + aoffB + 6144 + swk1);

#define MM_AB()                                                                 \
    __builtin_amdgcn_s_setprio(1);                                              \
    LG6();                                                                      \
    acc[0][0] = MFMA_BF16(af[0][0], bfv[0][0], acc[0][0]);                      \
    acc[0][0] = MFMA_BF16(af[0][1], bfv[0][1], acc[0][0]);                      \
    acc[0][1] = MFMA_BF16(af[0][0], bfv[1][0], acc[0][1]);                      \
    acc[0][1] = MFMA_BF16(af[0][1], bfv[1][1], acc[0][1]);                      \
    LG4();                                                                      \
    acc[1][0] = MFMA_BF16(af[1][0], bfv[0][0], acc[1][0]);                      \
    acc[1][0] = MFMA_BF16(af[1][1], bfv[0][1], acc[1][0]);                      \
    acc[1][1] = MFMA_BF16(af[1][0], bfv[1][0], acc[1][1]);                      \
    acc[1][1] = MFMA_BF16(af[1][1], bfv[1][1], acc[1][1]);                      \
    LG2();                                                                      \
    acc[2][0] = MFMA_BF16(af[2][0], bfv[0][0], acc[2][0]);                      \
    acc[2][0] = MFMA_BF16(af[2][1], bfv[0][1], acc[2][0]);                      \
    acc[2][1] = MFMA_BF16(af[2][0], bfv[1][0], acc[2][1]);                      \
    acc[2][1] = MFMA_BF16(af[2][1], bfv[1][1], acc[2][1]);                      \
    LG0();                                                                      \
    acc[3][0] = MFMA_BF16(af[3][0], bfv[0][0], acc[3][0]);                      \
    acc[3][0] = MFMA_BF16(af[3][1], bfv[0][1], acc[3][0]);                      \
    acc[3][1] = MFMA_BF16(af[3][0], bfv[1][0], acc[3][1]);                      \
    acc[3][1] = MFMA_BF16(af[3][1], bfv[1][1], acc[3][1]);                      \
    __builtin_amdgcn_s_setprio(0);

#define PH_B(L)                                                                 \
    bfv[2][0] = RD(L + boffB + 4096 + swk0); bfv[2][1] = RD(L + boffB + 4096 + swk1); \
    SB();                                                                       \
    bfv[3][0] = RD(L + boffB + 6144 + swk0); bfv[3][1] = RD(L + boffB + 6144 + swk1);

#define MM_B()                                                                  \
    __builtin_amdgcn_s_setprio(1);                                              \
    LG2();                                                                      \
    acc[0][2] = MFMA_BF16(af[0][0], bfv[2][0], acc[0][2]);                      \
    acc[0][2] = MFMA_BF16(af[0][1], bfv[2][1], acc[0][2]);                      \
    acc[1][2] = MFMA_BF16(af[1][0], bfv[2][0], acc[1][2]);                      \
    acc[1][2] = MFMA_BF16(af[1][1], bfv[2][1], acc[1][2]);                      \
    acc[2][2] = MFMA_BF16(af[2][0], bfv[2][0], acc[2][2]);                      \
    acc[2][2] = MFMA_BF16(af[2][1], bfv[2][1], acc[2][2]);                      \
    acc[3][2] = MFMA_BF16(af[3][0], bfv[2][0], acc[3][2]);                      \
    acc[3][2] = MFMA_BF16(af[3][1], bfv[2][1], acc[3][2]);                      \
    LG0();                                                                      \
    acc[0][3] = MFMA_BF16(af[0][0], bfv[3][0], acc[0][3]);                      \
    acc[0][3] = MFMA_BF16(af[0][1], bfv[3][1], acc[0][3]);                      \
    acc[1][3] = MFMA_BF16(af[1][0], bfv[3][0], acc[1][3]);                      \
    acc[1][3] = MFMA_BF16(af[1][1], bfv[3][1], acc[1][3]);                      \
    acc[2][3] = MFMA_BF16(af[2][0], bfv[3][0], acc[2][3]);                      \
    acc[2][3] = MFMA_BF16(af[2][1], bfv[3][1], acc[2][3]);                      \
    acc[3][3] = MFMA_BF16(af[3][0], bfv[3][0], acc[3][3]);                      \
    acc[3][3] = MFMA_BF16(af[3][1], bfv[3][1], acc[3][3]);                      \
    __builtin_amdgcn_s_setprio(0);

#define PH_A(L)                                                                 \
    af[0][0] = RD(L + aoffB + 8192 + swk0);  af[0][1] = RD(L + aoffB + 8192 + swk1);  \
    SB();                                                                       \
    af[1][0] = RD(L + aoffB + 10240 + swk0); af[1][1] = RD(L + aoffB + 10240 + swk1); \
    SB();                                                                       \
    af[2][0] = RD(L + aoffB + 12288 + swk0); af[2][1] = RD(L + aoffB + 12288 + swk1); \
    SB();                                                                       \
    af[3][0] = RD(L + aoffB + 14336 + swk0); af[3][1] = RD(L + aoffB + 14336 + swk1);

#define MM_A()                                                                  \
    __builtin_amdgcn_s_setprio(1);                                              \
    LG6();                                                                      \
    acc[4][2] = MFMA_BF16(af[0][0], bfv[2][0], acc[4][2]);                      \
    acc[4][2] = MFMA_BF16(af[0][1], bfv[2][1], acc[4][2]);                      \
    acc[4][3] = MFMA_BF16(af[0][0], bfv[3][0], acc[4][3]);                      \
    acc[4][3] = MFMA_BF16(af[0][1], bfv[3][1], acc[4][3]);                      \
    LG4();                                                                      \
    acc[5][2] = MFMA_BF16(af[1][0], bfv[2][0], acc[5][2]);                      \
    acc[5][2] = MFMA_BF16(af[1][1], bfv[2][1], acc[5][2]);                      \
    acc[5][3] = MFMA_BF16(af[1][0], bfv[3][0], acc[5][3]);                      \
    acc[5][3] = MFMA_BF16(af[1][1], bfv[3][1], acc[5][3]);                      \
    LG2();                                                                      \
    acc[6][2] = MFMA_BF16(af[2][0], bfv[2][0], acc[6][2]);                      \
    acc[6][2] = MFMA_BF16(af[2][1], bfv[2][1], acc[6][2]);                      \
    acc[6][3] = MFMA_BF16(af[2][0], bfv[3][0], acc[6][3]);                      \
    acc[6][3] = MFMA_BF16(af[2][1], bfv[3][1], acc[6][3]);                      \
    LG0();                                                                      \
    acc[7][2] = MFMA_BF16(af[3][0], bfv[2][0], acc[7][2]);                      \
    acc[7][2] = MFMA_BF16(af[3][1], bfv[2][1], acc[7][2]);                      \
    acc[7][3] = MFMA_BF16(af[3][0], bfv[3][0], acc[7][3]);                      \
    acc[7][3] = MFMA_BF16(af[3][1], bfv[3][1], acc[7][3]);                      \
    __builtin_amdgcn_s_setprio(0);

#define MM_0()                                                                  \
    __builtin_amdgcn_s_setprio(1);                                              \
    acc[4][0] = MFMA_BF16(af[0][0], bfv[0][0], acc[4][0]);                      \
    acc[4][0] = MFMA_BF16(af[0][1], bfv[0][1], acc[4][0]);                      \
    acc[4][1] = MFMA_BF16(af[0][0], bfv[1][0], acc[4][1]);                      \
    acc[4][1] = MFMA_BF16(af[0][1], bfv[1][1], acc[4][1]);                      \
    acc[5][0] = MFMA_BF16(af[1][0], bfv[0][0], acc[5][0]);                      \
    acc[5][0] = MFMA_BF16(af[1][1], bfv[0][1], acc[5][0]);                      \
    acc[5][1] = MFMA_BF16(af[1][0], bfv[1][0], acc[5][1]);                      \
    acc[5][1] = MFMA_BF16(af[1][1], bfv[1][1], acc[5][1]);                      \
    acc[6][0] = MFMA_BF16(af[2][0], bfv[0][0], acc[6][0]);                      \
    acc[6][0] = MFMA_BF16(af[2][1], bfv[0][1], acc[6][0]);                      \
    acc[6][1] = MFMA_BF16(af[2][0], bfv[1][0], acc[6][1]);                      \
    acc[6][1] = MFMA_BF16(af[2][1], bfv[1][1], acc[6][1]);                      \
    acc[7][0] = MFMA_BF16(af[3][0], bfv[0][0], acc[7][0]);                      \
    acc[7][0] = MFMA_BF16(af[3][1], bfv[0][1], acc[7][0]);                      \
    acc[7][1] = MFMA_BF16(af[3][0], bfv[1][0], acc[7][1]);                      \
    acc[7][1] = MFMA_BF16(af[3][1], bfv[1][1], acc[7][1]);                      \
    __builtin_amdgcn_s_setprio(0);

  const int nit = K >> 7;  // 32
#pragma unroll 1
  for (int t = 0; t < nit; ++t) {
    const int e = 2 * t, o = 2 * t + 1;
    const int e2 = (e + 2 > ktmax) ? ktmax : e + 2;
    const int o2 = (o + 2 > ktmax) ? ktmax : o + 2;
    const char* L0 = lds;
    const char* L1 = lds + 65536;
    bf16x8 af[4][2], bfv[4][2];

    PH_AB(L0); STG_HT(0, mbase, 0, 1, o); BARRIER(); MM_AB(); BARRIER();
    PH_B(L0); STG_HT(0, mbase, 1, 1, o); BARRIER(); MM_B(); BARRIER();
    PH_A(L0); STG_HT(1, nbase, 0, 0, e2); BARRIER(); MM_A(); BARRIER();
    STG_HT(1, nbase, 1, 0, e2); VM4(); BARRIER(); MM_0(); BARRIER();
    PH_AB(L1); STG_HT(0, mbase, 0, 0, e2); BARRIER(); MM_AB(); BARRIER();
    PH_B(L1); STG_HT(0, mbase, 1, 0, e2); BARRIER(); MM_B(); BARRIER();
    PH_A(L1); STG_HT(1, nbase, 0, 1, o2); BARRIER(); MM_A(); BARRIER();
    STG_HT(1, nbase, 1, 1, o2); VM4(); BARRIER(); MM_0(); BARRIER();
  }
#undef STG_HT
#undef PH_AB
#undef PH_A
#undef PH_B
#undef MM_AB
#undef MM_A
#undef MM_B
#undef MM_0
#undef BARRIER
#undef SB
#undef LG6
#undef LG4
#undef LG2
#undef LG0
#undef VM4
#undef RD
  const int crow = mbase + wm * 128 + g * 4;
  const int ccol = nbase + wn * 64 + qcol;
#pragma unroll
  for (int mi = 0; mi < 8; ++mi)
#pragma unroll
    for (int ni = 0; ni < 4; ++ni)
#pragma unroll
      for (int r = 0; r < 4; ++r)
        C[(long)(crow + mi * 16 + r) * N + (ccol + ni * 16)] = f2bf(acc[mi][ni][r]);
}

// ---------- bf16 GEMM 128^2 (m97 structure) — kept for GEMM2 (fp32 out) ----------
__global__ __launch_bounds__(256, 2) void gemm_bt(const unsigned short* __restrict__ A,
                                                  const unsigned short* __restrict__ B,
                                                  float* __restrict__ C, int N, int K) {
  __shared__ unsigned short As[128 * 32] __attribute__((aligned(16)));
  __shared__ unsigned short Bs[128 * 32] __attribute__((aligned(16)));
  const int tid = threadIdx.x;
  const int lane = tid & 63;
  const int wv = tid >> 6;
  const int wr = wv >> 1, wc = wv & 1;
  const int mbase = blockIdx.y * 128, nbase = blockIdx.x * 128;
  const int r16 = lane >> 2;
  const int k8 = (lane & 3) * 8;
  const unsigned short* Ag0 = A + (mbase + wv * 32 + r16) * K + k8;
  const unsigned short* Ag1 = Ag0 + 16 * K;
  const unsigned short* Bg0 = B + (nbase + wv * 32 + r16) * K + k8;
  const unsigned short* Bg1 = Bg0 + 16 * K;
  unsigned short* Asl = As + wv * 1024 + lane * 8;
  unsigned short* Bsl = Bs + wv * 1024 + lane * 8;
  f32x4 acc[4][4];
#pragma unroll
  for (int i = 0; i < 4; ++i)
#pragma unroll
    for (int j = 0; j < 4; ++j) { acc[i][j][0]=0.f; acc[i][j][1]=0.f; acc[i][j][2]=0.f; acc[i][j][3]=0.f; }
  const int rowA = (wr * 64 + (lane & 15)) * 32 + (lane >> 4) * 8;
  const int colB = (wc * 64 + (lane & 15)) * 32 + (lane >> 4) * 8;
  for (int kt = 0; kt < K; kt += 32) {
    gload16(Ag0 + kt, Asl);
    gload16(Ag1 + kt, Asl + 512);
    gload16(Bg0 + kt, Bsl);
    gload16(Bg1 + kt, Bsl + 512);
    __syncthreads();
    bf16x8 af[4], bfr[4];
#pragma unroll
    for (int mi = 0; mi < 4; ++mi) af[mi] = *(const bf16x8*)(As + rowA + mi * 512);
#pragma unroll
    for (int ni = 0; ni < 4; ++ni) bfr[ni] = *(const bf16x8*)(Bs + colB + ni * 512);
#pragma unroll
    for (int mi = 0; mi < 4; ++mi)
#pragma unroll
      for (int ni = 0; ni < 4; ++ni)
        acc[mi][ni] = MFMA_BF16(af[mi], bfr[ni], acc[mi][ni]);
    __syncthreads();
  }
  const int crow = mbase + wr * 64 + (lane >> 4) * 4;
  const int ccol = nbase + wc * 64 + (lane & 15);
#pragma unroll
  for (int mi = 0; mi < 4; ++mi)
#pragma unroll
    for (int ni = 0; ni < 4; ++ni)
#pragma unroll
      for (int r = 0; r < 4; ++r)
        C[(long)(crow + mi * 16 + r) * N + (ccol + ni * 16)] = acc[mi][ni][r];
}

// ---------- merged RoPE(q,k) + V-scatter (both read bf16 qkv) ----------
__global__ __launch_bounds__(256) void rope_scat(const unsigned short* __restrict__ qkv,
                                                 const int* __restrict__ pos,
                                                 unsigned short* __restrict__ Qb,
                                                 unsigned short* __restrict__ Kg,
                                                 unsigned short* __restrict__ VgT) {
  if (blockIdx.x < 10240) {
    int gw = blockIdx.x * 4 + (threadIdx.x >> 6);
    int lane = threadIdx.x & 63;
    int t = gw >> 5, h = gw & 31;
    int p = pos[t];
    int b = (t < 256) ? 0 : (t < 768) ? 1 : (t < 896) ? 2 : 3;
    float invf = exp2f(-(float)lane * 0.2076205059304601f);  // log2(10000)/64
    float ang = (float)p * invf;
    float sv = sinf(ang), cv = cosf(ang);
    const unsigned short* src = qkv + (long)t * 12288 + h * 128 + lane;
    float q1 = bf2f(src[0]), q2 = bf2f(src[64]);
    float k1 = bf2f(src[4096]), k2 = bf2f(src[4096 + 64]);
    const float scl = 0.08838834764831845f;  // 1/sqrt(128), folded into Q
    unsigned short* qd = Qb + (long)t * 4096 + h * 128 + lane;
    qd[0]  = f2bf((q1 * cv - q2 * sv) * scl);
    qd[64] = f2bf((q2 * cv + q1 * sv) * scl);
    unsigned short* kd = Kg + ((long)(b * 32 + h) * 2048 + p) * 128 + lane;
    kd[0]  = f2bf(k1 * cv - k2 * sv);
    kd[64] = f2bf(k2 * cv + k1 * sv);
    return;
  }
  int bid = blockIdx.x - 10240;        // 0..639
  int tt = bid % 20, h = bid / 20;
  int b = (tt < 4) ? 0 : (tt < 12) ? 1 : (tt < 14) ? 2 : 3;
  int q0 = (b == 0) ? 0 : (b == 1) ? 256 : (b == 2) ? 768 : 896;
  int hist = (b == 0) ? 1792 : (b == 1) ? 1024 : (b == 2) ? 1536 : 768;
  int t0 = tt * 64;
  int jb = hist + t0 - q0;
  __shared__ unsigned short vt[64][130];
  int tid = threadIdx.x;
  int jj0 = tid >> 5, c4 = (tid & 31) * 4;
#pragma unroll
  for (int ps = 0; ps < 8; ++ps) {
    int jj = jj0 + ps * 8;
    ushort4 v = *(const ushort4*)(qkv + (long)(t0 + jj) * 12288 + 8192 + h * 128 + c4);
    *(ushort4*)&vt[jj][c4] = v;
  }
  __syncthreads();
  int d = tid >> 1, half = tid & 1;
  unsigned short* dst = VgT + ((long)(b * 32 + h) * 128 + d) * 2048 + jb + half * 32;
  int j0 = half * 32;
#pragma unroll
  for (int w = 0; w < 4; ++w) {
    uint4 u;
    u.x = vt[j0 + w * 8 + 0][d] | ((unsigned)vt[j0 + w * 8 + 1][d] << 16);
    u.y = vt[j0 + w * 8 + 2][d] | ((unsigned)vt[j0 + w * 8 + 3][d] << 16);
    u.z = vt[j0 + w * 8 + 4][d] | ((unsigned)vt[j0 + w * 8 + 5][d] << 16);
    u.w = vt[j0 + w * 8 + 6][d] | ((unsigned)vt[j0 + w * 8 + 7][d] << 16);
    ((uint4*)dst)[w] = u;
  }
}

// ---------- flash attention PARTIAL over one KV chunk of 512 (QBLK=128, fp16 partials) ----------
__global__ __launch_bounds__(512) void attn_part(const unsigned short* __restrict__ Qb,
                                                 const unsigned short* __restrict__ Kg,
                                                 const unsigned short* __restrict__ VgT,
                                                 const int* __restrict__ pos,
                                                 unsigned short* __restrict__ Opart,
                                                 float* __restrict__ ml) {
  __shared__ char lds[32768] __attribute__((aligned(16)));
  int qt = blockIdx.x, h = blockIdx.y, ck = blockIdx.z;
  int tid = threadIdx.x;
  int wv = tid >> 6, lane = tid & 63;
  int b = (qt < 2) ? 0 : (qt < 6) ? 1 : (qt < 7) ? 2 : 3;
  int qb = qt * 128 + wv * 16;
  int qcol = lane & 15, g = lane >> 4;
  int t = qb + qcol;
  int p = pos[t];
  int pmax_wave = pos[qb + 15];
  int pmax_blk = pos[qt * 128 + 127];
  int kv_begin = ck * 512;
  if (kv_begin > pmax_blk) return;
  int kv_end = pmax_blk + 1;
  if (kv_end > kv_begin + 512) kv_end = kv_begin + 512;
  int nt = (kv_end - kv_begin + 31) >> 5;

  const char* KbhB = (const char*)(Kg + (long)(b * 32 + h) * 2048 * 128);
  const char* VbhB = (const char*)(VgT + (long)(b * 32 + h) * 128 * 2048);

  const int d0 = tid * 16;
  const int ksrc0 = d0 ^ (((d0 >> 8) & 7) << 4);
  const int vrow0 = d0 >> 6;
  const int vsrc0 = vrow0 * 4096 + ((d0 & 63) ^ ((vrow0 & 3) << 4));

#define STAGE(kv0, buf)                                                     \
  {                                                                          \
    const char* Ksrc = KbhB + (long)(kv0) * 256;                             \
    const char* Vsrc = VbhB + (long)(kv0) * 2;                               \
    char* Kd = lds + (buf) * 8192;                                           \
    char* Vd = lds + 16384 + (buf) * 8192;                                   \
    gload16(Ksrc + ksrc0, Kd + d0);                                          \
    gload16(Vsrc + vsrc0, Vd + d0);                                          \
  }

  const unsigned short* Qp = Qb + (long)t * 4096 + h * 128 + g * 8;
  bf16x8 qf[4];
#pragma unroll
  for (int c = 0; c < 4; ++c) qf[c] = *(const bf16x8*)(Qp + c * 32);

  const int kswz = ((qcol & 7) << 4);
  const int vswz = (g * 16) ^ ((qcol & 3) << 4);

  float m = -1e30f, lsum = 0.f;
  f32x4 o[8];
#pragma unroll
  for (int i = 0; i < 8; ++i) { o[i][0]=0.f; o[i][1]=0.f; o[i][2]=0.f; o[i][3]=0.f; }

  STAGE(kv_begin, 0);

  for (int it = 0; it < nt; ++it) {
    int cur = it & 1;
    int kv0 = kv_begin + it * 32;
    if (it + 1 < nt) {
      STAGE(kv0 + 32, cur ^ 1);
      asm volatile("s_waitcnt vmcnt(2)" ::: "memory");
    } else {
      asm volatile("s_waitcnt vmcnt(0)" ::: "memory");
    }
    __builtin_amdgcn_sched_barrier(0);
    __builtin_amdgcn_s_barrier();
    if (kv0 <= pmax_wave) {
      const char* Kc = lds + cur * 8192;
      const char* Vc = lds + 16384 + cur * 8192;
      f32x4 s0, s1;
      s0[0]=0.f;s0[1]=0.f;s0[2]=0.f;s0[3]=0.f;
      s1[0]=0.f;s1[1]=0.f;s1[2]=0.f;s1[3]=0.f;
#pragma unroll
      for (int c = 0; c < 4; ++c) {
        int colb = (g * 16 + c * 64) ^ kswz;
        bf16x8 k0 = *(const bf16x8*)(Kc + qcol * 256 + colb);
        bf16x8 k1 = *(const bf16x8*)(Kc + 4096 + qcol * 256 + colb);
        s0 = MFMA_BF16(k0, qf[c], s0);
        s1 = MFMA_BF16(k1, qf[c], s1);
      }
      int kvg = kv0 + g * 4;
      float sv[8];
#pragma unroll
      for (int r = 0; r < 4; ++r) {
        sv[r]     = (kvg + r      <= p) ? s0[r] : -1e30f;
        sv[r + 4] = (kvg + 16 + r <= p) ? s1[r] : -1e30f;
      }
      float mt = sv[0];
#pragma unroll
      for (int i = 1; i < 8; ++i) mt = fmaxf(mt, sv[i]);
      mt = fmaxf(mt, __shfl_xor(mt, 16));
      mt = fmaxf(mt, __shfl_xor(mt, 32));
      float mnew = fmaxf(m, mt);
      float corr = __expf(m - mnew);
      float ssum = 0.f;
      float pvv[8];
#pragma unroll
      for (int i = 0; i < 8; ++i) { pvv[i] = __expf(sv[i] - mnew); ssum += pvv[i]; }
      ssum += __shfl_xor(ssum, 16);
      ssum += __shfl_xor(ssum, 32);
      lsum = lsum * corr + ssum;
      m = mnew;
#pragma unroll
      for (int df = 0; df < 8; ++df) o[df] *= corr;
      unsigned pk0 = (unsigned)f2bf(pvv[0]) | ((unsigned)f2bf(pvv[1]) << 16);
      unsigned pk1 = (unsigned)f2bf(pvv[2]) | ((unsigned)f2bf(pvv[3]) << 16);
      unsigned pk2 = (unsigned)f2bf(pvv[4]) | ((unsigned)f2bf(pvv[5]) << 16);
      unsigned pk3 = (unsigned)f2bf(pvv[6]) | ((unsigned)f2bf(pvv[7]) << 16);
      int s0l = ((g & 1) * 32) + qcol;
      int s1l = s0l + 16;
      unsigned a0 = (unsigned)__shfl((int)pk0, s0l), a1 = (unsigned)__shfl((int)pk1, s0l);
      unsigned a2 = (unsigned)__shfl((int)pk2, s0l), a3 = (unsigned)__shfl((int)pk3, s0l);
      unsigned b0 = (unsigned)__shfl((int)pk0, s1l), b1 = (unsigned)__shfl((int)pk1, s1l);
      unsigned b2 = (unsigned)__shfl((int)pk2, s1l), b3 = (unsigned)__shfl((int)pk3, s1l);
      bool hi = (g >= 2);
      u32x4 wv4;
      wv4[0] = hi ? a2 : a0; wv4[1] = hi ? a3 : a1;
      wv4[2] = hi ? b2 : b0; wv4[3] = hi ? b3 : b1;
      bf16x8 pfrag = __builtin_bit_cast(bf16x8, wv4);
#pragma unroll
      for (int df = 0; df < 8; ++df) {
        bf16x8 vf = *(const bf16x8*)(Vc + (df * 16 + qcol) * 64 + vswz);
        o[df] = MFMA_BF16(vf, pfrag, o[df]);
      }
    }
    __builtin_amdgcn_s_barrier();
  }
#undef STAGE
  // write unnormalized partial O (fp16) and (m, l) fp32
  long pbase = (long)((qt * 32 + h) * 4 + ck);
  unsigned short* Op = Opart + pbase * 16384 + (wv * 16 + qcol) * 128 + g * 4;
#pragma unroll
  for (int df = 0; df < 8; ++df) {
    ushort4 hv;
    hv.x = f2h(o[df][0]); hv.y = f2h(o[df][1]);
    hv.z = f2h(o[df][2]); hv.w = f2h(o[df][3]);
    *(ushort4*)(Op + df * 16) = hv;
  }
  if (g == 0) {
    float* mlp = ml + pbase * 256 + (wv * 16 + qcol) * 2;
    mlp[0] = m;
    mlp[1] = lsum;
  }
}

// ---------- combine partials across KV chunks (fp16 partials in) ----------
__global__ __launch_bounds__(256) void attn_comb(const unsigned short* __restrict__ Opart,
                                                 const float* __restrict__ ml,
                                                 const int* __restrict__ pos,
                                                 unsigned short* __restrict__ Ao) {
  int qt = blockIdx.x, h = blockIdx.y;   // qt over 64-row tiles (0..19)
  int tid = threadIdx.x;
  int q = tid >> 2, dq = (tid & 3) * 32;
  int t = qt * 64 + q;
  int p = pos[t];
  int ncv = (p >> 9) + 1;
  if (ncv > 4) ncv = 4;
  int bigqt = qt >> 1;
  int row = (qt & 1) * 64 + q;           // row within 128-row partial
  long base = (long)(bigqt * 32 + h) * 4;
  float M = -1e30f;
#pragma unroll
  for (int c = 0; c < 4; ++c)
    if (c < ncv) M = fmaxf(M, ml[(base + c) * 256 + row * 2]);
  float L = 0.f;
#pragma unroll
  for (int c = 0; c < 4; ++c)
    if (c < ncv) L += __expf(ml[(base + c) * 256 + row * 2] - M) * ml[(base + c) * 256 + row * 2 + 1];
  f32x4 acc[8];
#pragma unroll
  for (int i = 0; i < 8; ++i) { acc[i][0]=0.f; acc[i][1]=0.f; acc[i][2]=0.f; acc[i][3]=0.f; }
#pragma unroll
  for (int c = 0; c < 4; ++c)
    if (c < ncv) {
      float wc = __expf(ml[(base + c) * 256 + row * 2] - M);
      const ushort4* src = (const ushort4*)(Opart + (base + c) * 16384 + row * 128 + dq);
#pragma unroll
      for (int i = 0; i < 8; ++i) {
        ushort4 s = src[i];
        acc[i][0] += wc * h2f(s.x); acc[i][1] += wc * h2f(s.y);
        acc[i][2] += wc * h2f(s.z); acc[i][3] += wc * h2f(s.w);
      }
    }
  float inv = 1.f / L;
  unsigned short* dst = Ao + (long)t * 4096 + h * 128 + dq;
#pragma unroll
  for (int i = 0; i < 8; ++i) {
    ushort4 ov;
    ov.x = f2bf(acc[i][0] * inv); ov.y = f2bf(acc[i][1] * inv);
    ov.z = f2bf(acc[i][2] * inv); ov.w = f2bf(acc[i][3] * inv);
    *(ushort4*)(dst + i * 4) = ov;
  }
}

// ---------- launch ----------
extern "C" void kernel_launch(void* const* d_in, const int* in_sizes, int n_in,
                              void* d_out, int out_size, void* d_ws, size_t ws_size,
                              hipStream_t stream) {
  const float* hs   = (const float*)d_in[0];
  const float* wq   = (const float*)d_in[1];
  const float* wk   = (const float*)d_in[2];
  const float* wvp  = (const float*)d_in[3];
  const float* wo   = (const float*)d_in[4];
  const float* pkey = (const float*)d_in[5];
  const float* pval = (const float*)d_in[6];
  const int* pos    = (const int*)d_in[7];
  const int* btab   = (const int*)d_in[8];

  unsigned short* Wqkv = (unsigned short*)d_ws;                       // [12288][4096] bf16
  unsigned short* Wo   = Wqkv + (size_t)12288 * 4096;                 // [4096][4096]
  unsigned short* Hb   = Wo + (size_t)4096 * 4096;                    // [1280][4096]
  unsigned short* qkvb = Hb + (size_t)1280 * 4096;                    // [1280][12288] bf16
  unsigned short* Qbf  = qkvb + (size_t)1280 * 12288 * 2;             // (region kept same size as old fp32)
  unsigned short* Kg   = Qbf + (size_t)1280 * 4096;                   // [4][32][2048][128]
  unsigned short* VgT  = Kg + (size_t)4 * 32 * 2048 * 128;            // [4][32][128][2048]
  unsigned short* Aob  = VgT + (size_t)4 * 32 * 2048 * 128;           // [1280][4096]
  unsigned short* Opart = (unsigned short*)d_ws;                      // overlay Wqkv (dead after gemm1): 41.9MB fp16
  float* mlb   = (float*)((char*)d_ws + 83886080);                    // +1.31MB < 100.7MB
  if (ws_size < 362807296ull) return;

  cvt_gather<<<6656, 256, 0, stream>>>(wq, wk, wvp, wo, hs, Wqkv, pkey, pval, btab, Kg, VgT);

  gemm256<<<dim3(48, 5), 512, 131072, stream>>>(Hb, Wqkv, qkvb, 12288, 4096);
  rope_scat<<<10880, 256, 0, stream>>>(qkvb, pos, Qbf, Kg, VgT);
  attn_part<<<dim3(10, 32, 4), 512, 0, stream>>>(Qbf, Kg, VgT, pos, Opart, mlb);
  attn_comb<<<dim3(20, 32), 256, 0, stream>>>(Opart, mlb, pos, Aob);
  gemm_bt<<<dim3(32, 10), 256, 0, stream>>>(Aob, Wo, (float*)d_out, 4096, 4096);
}

// Round 16
// 432.799 us; speedup vs baseline: 1.0258x; 1.0258x over previous
//
#include <hip/hip_runtime.h>
#include <stdint.h>

// ---------- problem constants (hardcoded from reference) ----------
// B=4, Q_LENS={256,512,128,384}, HIST={1792,1024,1536,768}
// Q_START={0,256,768,896}, KV_LENS={2048,1536,1664,1152}
// H=32, D=128, HID=4096, BS=64, MAX_KV=2048, MAX_BLOCKS=32, TOTAL_Q=1280

typedef __attribute__((ext_vector_type(8))) short bf16x8;
typedef __attribute__((ext_vector_type(4))) float f32x4;
typedef __attribute__((ext_vector_type(4))) unsigned int u32x4;

__device__ __forceinline__ unsigned short f2bf(float f) {
  unsigned int u = __float_as_uint(f);
  u += 0x7fffu + ((u >> 16) & 1u);
  return (unsigned short)(u >> 16);
}
__device__ __forceinline__ float bf2f(unsigned short u) {
  return __uint_as_float(((unsigned int)u) << 16);
}
__device__ __forceinline__ unsigned short f2h(float f) {
  _Float16 h = (_Float16)f;
  return __builtin_bit_cast(unsigned short, h);
}
__device__ __forceinline__ float h2f(unsigned short u) {
  return (float)__builtin_bit_cast(_Float16, u);
}

// ---------- fused pass 1: fp32->bf16 converts (2 elems/thread, half-split) + gather tail ----------
// cvt blocks 0..35327: thread j handles float4 j and j+9043968 — both loads
// per-instruction coalesced (consecutive lanes -> consecutive float4), issued
// back-to-back for 2-deep memory parallelism. Gather blocks at the END (R14
// ordering — gather-first regressed in R15).
__global__ __launch_bounds__(256) void cvt_gather(const float* __restrict__ wq,
                                                  const float* __restrict__ wk,
                                                  const float* __restrict__ wv,
                                                  const float* __restrict__ wo,
                                                  const float* __restrict__ hs,
                                                  unsigned short* __restrict__ dst,
                                                  const float* __restrict__ pk,
                                                  const float* __restrict__ pv,
                                                  const int* __restrict__ btab,
                                                  unsigned short* __restrict__ Kg,
                                                  unsigned short* __restrict__ VgT) {
  if (blockIdx.x < 35328) {
    const long half = 9043968;  // 18087936 float4 / 2
    long j = (long)blockIdx.x * 256 + threadIdx.x;
    long i0 = j, i1 = j + half;
    const float* s0; long o0;
    if (i0 < 4194304)        { s0 = wq; o0 = i0; }
    else if (i0 < 8388608)   { s0 = wk; o0 = i0 - 4194304; }
    else                     { s0 = wv; o0 = i0 - 8388608; }   // i0 < 9043968 < 12582912
    const float* s1; long o1;
    if (i1 < 12582912)       { s1 = wv; o1 = i1 - 8388608; }
    else if (i1 < 16777216)  { s1 = wo; o1 = i1 - 12582912; }
    else                     { s1 = hs; o1 = i1 - 16777216; }
    float4 v0 = ((const float4*)s0)[o0];
    float4 v1 = ((const float4*)s1)[o1];
    ushort4 a, b;
    a.x = f2bf(v0.x); a.y = f2bf(v0.y); a.z = f2bf(v0.z); a.w = f2bf(v0.w);
    b.x = f2bf(v1.x); b.y = f2bf(v1.y); b.z = f2bf(v1.z); b.w = f2bf(v1.w);
    ((ushort4*)dst)[i0] = a;
    ((ushort4*)dst)[i1] = b;
    return;
  }
  // ---- gather history K,V (tail blocks, R14 ordering) ----
  int gid = blockIdx.x - 35328;        // 0..2559
  int gx = gid % 80, h = gid / 80;
  int b = (gx < 28) ? 0 : (gx < 44) ? 1 : (gx < 68) ? 2 : 3;
  int jt = gx - ((b == 0) ? 0 : (b == 1) ? 28 : (b == 2) ? 44 : 68);
  int slot0 = btab[b * 32 + jt] * 64;
  int jbase = jt * 64;
  __shared__ unsigned short vt[64][130];
  int tid = threadIdx.x;
  int jj0 = tid >> 5, c4 = (tid & 31) * 4;
#pragma unroll
  for (int ps = 0; ps < 8; ++ps) {
    int jj = jj0 + ps * 8;
    long off = ((long)(slot0 + jj) * 32 + h) * 128 + c4;
    float4 kk = *(const float4*)(pk + off);
    ushort4 ko;
    ko.x = f2bf(kk.x); ko.y = f2bf(kk.y); ko.z = f2bf(kk.z); ko.w = f2bf(kk.w);
    *(ushort4*)(Kg + ((long)(b * 32 + h) * 2048 + jbase + jj) * 128 + c4) = ko;
    float4 vv = *(const float4*)(pv + off);
    ushort2 a, c;
    a.x = f2bf(vv.x); a.y = f2bf(vv.y); c.x = f2bf(vv.z); c.y = f2bf(vv.w);
    *(ushort2*)&vt[jj][c4] = a;
    *(ushort2*)&vt[jj][c4 + 2] = c;
  }
  __syncthreads();
  int d = tid >> 1, half2 = tid & 1;
  unsigned short* dstv = VgT + ((long)(b * 32 + h) * 128 + d) * 2048 + jbase + half2 * 32;
  int j0 = half2 * 32;
#pragma unroll
  for (int w = 0; w < 4; ++w) {
    uint4 u;
    u.x = vt[j0 + w * 8 + 0][d] | ((unsigned)vt[j0 + w * 8 + 1][d] << 16);
    u.y = vt[j0 + w * 8 + 2][d] | ((unsigned)vt[j0 + w * 8 + 3][d] << 16);
    u.z = vt[j0 + w * 8 + 4][d] | ((unsigned)vt[j0 + w * 8 + 5][d] << 16);
    u.w = vt[j0 + w * 8 + 6][d] | ((unsigned)vt[j0 + w * 8 + 7][d] << 16);
    ((uint4*)dstv)[w] = u;
  }
}

__device__ __forceinline__ void gload16(const void* g, void* l) {
  __builtin_amdgcn_global_load_lds(
      (const __attribute__((address_space(1))) unsigned int*)(g),
      (__attribute__((address_space(3))) unsigned int*)(l), 16, 0, 0);
}

#define MFMA_BF16(a, b, c) __builtin_amdgcn_mfma_f32_16x16x32_bf16((a), (b), (c), 0, 0, 0)

// ---------- 256x256 8-phase bf16 GEMM (frozen R13: counted lgkm cascades, bf16 out) ----------
__global__ __launch_bounds__(512, 2) void gemm256(const unsigned short* __restrict__ A,
                                                  const unsigned short* __restrict__ B,
                                                  unsigned short* __restrict__ C, int N, int K) {
  extern __shared__ char lds[];  // 131072
  const int tid = threadIdx.x;
  const int lane = tid & 63;
  const int wid = tid >> 6;
  const int wm = wid >> 2, wn = wid & 3;
  const int qcol = lane & 15, g = lane >> 4;
  const int mbase = blockIdx.y * 256, nbase = blockIdx.x * 256;
  const long Kb = (long)K * 2;
  const int ktmax = (K >> 6) - 1;  // 63

  const char* Ab = (const char*)A;
  const char* Bb = (const char*)B;
  const int srow = tid >> 3;
  const int ssw = ((tid & 7) ^ (srow & 7)) * 16;  // pre-swizzled 16B source slot

#define STG_HT(MB, GB, HF, BUF, KT) {                                          \
    long ro = (long)((GB) + (HF) * 128 + srow) * Kb + (long)(KT) * 128 + ssw;  \
    char* d = lds + (BUF) * 65536 + (MB) * 32768 + (HF) * 16384 + tid * 16;    \
    const char* sp = (MB) ? Bb : Ab;                                           \
    gload16(sp + ro, d);                                                       \
    gload16(sp + ro + 64 * Kb, d + 8192);                                      \
  }

  const int aoffB = wm * 16384 + qcol * 128;                               // + mi*2048 + swk
  const int boffB = 32768 + (wn >> 1) * 16384 + ((wn & 1) * 64 + qcol) * 128;  // + ni*2048 + swk
  const int swk0 = ((g) ^ (qcol & 7)) * 16;
  const int swk1 = ((4 + g) ^ (qcol & 7)) * 16;

  f32x4 acc[8][4];
#pragma unroll
  for (int i = 0; i < 8; ++i)
#pragma unroll
    for (int j = 0; j < 4; ++j) { acc[i][j][0]=0.f; acc[i][j][1]=0.f; acc[i][j][2]=0.f; acc[i][j][3]=0.f; }

#define SB()      __builtin_amdgcn_sched_barrier(0)
#define BARRIER() { __builtin_amdgcn_sched_barrier(0); __builtin_amdgcn_s_barrier(); }
#define LG6()     { asm volatile("s_waitcnt lgkmcnt(6)" ::: "memory"); SB(); }
#define LG4()     { asm volatile("s_waitcnt lgkmcnt(4)" ::: "memory"); SB(); }
#define LG2()     { asm volatile("s_waitcnt lgkmcnt(2)" ::: "memory"); SB(); }
#define LG0()     { asm volatile("s_waitcnt lgkmcnt(0)" ::: "memory"); SB(); }
#define VM4()     { asm volatile("s_waitcnt vmcnt(4)" ::: "memory"); SB(); }
#define RD(p)     (*(const bf16x8*)(p))

  STG_HT(0, mbase, 0, 0, 0); STG_HT(0, mbase, 1, 0, 0);
  STG_HT(1, nbase, 0, 0, 0); STG_HT(1, nbase, 1, 0, 0);
  STG_HT(1, nbase, 0, 1, 1); STG_HT(1, nbase, 1, 1, 1);
  VM4();
  __builtin_amdgcn_s_barrier();

#define PH_AB(L)                                                                \
    af[0][0] = RD(L + aoffB + swk0);        af[0][1] = RD(L + aoffB + swk1);    \
    SB();                                                                       \
    bfv[0][0] = RD(L + boffB + swk0);       bfv[0][1] = RD(L + boffB + swk1);   \
    bfv[1][0] = RD(L + boffB + 2048 + swk0); bfv[1][1] = RD(L + boffB + 2048 + swk1); \
    SB();                                                                       \
    af[1][0] = RD(L + aoffB + 2048 + swk0); af[1][1] = RD(L + aoffB + 2048 + swk1); \
    SB();                                                                       \
    af[2][0] = RD(L + aoffB + 4096 + swk0); af[2][1] = RD(L + aoffB + 4096 + swk1); \
    SB();                                                                       \
    af[3][0] = RD(L + aoffB + 6144 + swk0); af[3][1] = RD(L + aoffB + 6144 + swk1);

#define MM_AB()                                                                 \
    __builtin_amdgcn_s_setprio(1);                                              \
    LG6();                                                                      \
    acc[0][0] = MFMA_BF16(af[0][0], bfv[0][0], acc[0][0]);                      \
    acc[0][0] = MFMA_BF16(af[0][1], bfv[0][1], acc[0][0]);                      \
    acc[0][1] = MFMA_BF16(af[0][0], bfv[1][0], acc[0][1]);                      \
    acc[0][1] = MFMA_BF16(af[0][1], bfv[1][1], acc[0][1]);                      \
    LG4();                                                                      \
    acc[1][0] = MFMA_BF16(af[1][0], bfv[0][0], acc[1][0]);                      \
    acc[1][0] = MFMA_BF16(af[1][1], bfv[0][1], acc[1][0]);                      \
    acc[1][1] = MFMA_BF16(af[1][0], bfv[1][0], acc[1][1]);                      \
    acc[1][1] = MFMA_BF16(af[1][1], bfv[1][1], acc[1][1]);                      \
    LG2();                                                                      \
    acc[2][0] = MFMA_BF16(af[2][0], bfv[0][0], acc[2][0]);                      \
    acc[2][0] = MFMA_BF16(af[2][1], bfv[0][1], acc[2][0]);                      \
    acc[2][1] = MFMA_BF16(af[2][0], bfv[1][0], acc[2][1]);                      \
    acc[2][1] = MFMA_BF16(af[2][1], bfv[1][1], acc[2][1]);                      \
    LG0();                                                                      \
    acc[3][0] = MFMA_BF16(af[3][0], bfv[0][0], acc[3][0]);                      \
    acc[3][0] = MFMA_BF16(af[3][1], bfv[0][1], acc[3][0]);                      \
    acc[3][1] = MFMA_BF16(af[3][0], bfv[1][0], acc[3][1]);                      \
    acc[3][1] = MFMA_BF16(af[3][1], bfv[1][1], acc[3][1]);                      \
    __builtin_amdgcn_s_setprio(0);

#define PH_B(L)                                                                 \
    bfv[2][0] = RD(L + boffB + 4096 + swk0); bfv[2][1] = RD(L + boffB + 4096 + swk1); \
    SB();                                                                       \
    bfv[3][0] = RD(L + boffB + 6144 + swk0); bfv[3][1] = RD(L + boffB + 6144 + swk1);

#define MM_B()                                                                  \
    __builtin_amdgcn_s_setprio(1);                                              \
    LG2();                                                                      \
    acc[0][2] = MFMA_BF16(af[0][0], bfv[2][0], acc[0][2]);                      \
    acc[0][2] = MFMA_BF16(af[0][1], bfv[2][1], acc[0][2]);                      \
    acc[1][2] = MFMA_BF16(af[1][0], bfv[2][0], acc[1][2]);                      \
    acc[1][2] = MFMA_BF16(af[1][1], bfv[2][1], acc[1][2]);                      \
    acc[2][2] = MFMA_BF16(af[2][0], bfv[2][0], acc[2][2]);                      \
    acc[2][2] = MFMA_BF16(af[2][1], bfv[2][1], acc[2][2]);                      \
    acc[3][2] = MFMA_BF16(af[3][0], bfv[2][0], acc[3][2]);                      \
    acc[3][2] = MFMA_BF16(af[3][1], bfv[2][1], acc[3][2]);                      \
    LG0();                                                                      \
    acc[0][3] = MFMA_BF16(af[0][0], bfv[3][0], acc[0][3]);                      \
    acc[0][3] = MFMA_BF16(af[0][1], bfv[3][1], acc[0][3]);                      \
    acc[1][3] = MFMA_BF16(af[1][0], bfv[3][0], acc[1][3]);                      \
    acc[1][3] = MFMA_BF16(af[1][1], bfv[3][1], acc[1][3]);                      \
    acc[2][3] = MFMA_BF16(af[2][0], bfv[3][0], acc[2][3]);                      \
    acc[2][3] = MFMA_BF16(af[2][1], bfv[3][1], acc[2][3]);                      \
    acc[3][3] = MFMA_BF16(af[3][0], bfv[3][0], acc[3][3]);                      \
    acc[3][3] = MFMA_BF16(af[3][1], bfv[3][1], acc[3][3]);                      \
    __builtin_amdgcn_s_setprio(0);

#define PH_A(L)                                                                 \
    af[0][0] = RD(L + aoffB + 8192 + swk0);  af[0][1] = RD(L + aoffB + 8192 + swk1);  \
    SB();                                                                       \
    af[1][0] = RD(L + aoffB + 10240 + swk0); af[1][1] = RD(L + aoffB + 10240 + swk1); \
    SB();                                                                       \
    af[2][0] = RD(L + aoffB + 12288 + swk0); af[2][1] = RD(L + aoffB + 12288 + swk1); \
    SB();                                                                       \
    af[3][0] = RD(L + aoffB + 14336 + swk0); af[3][1] = RD(L + aoffB + 14336 + swk1);

#define MM_A()                                                                  \
    __builtin_amdgcn_s_setprio(1);                                              \
    LG6();                                                                      \
    acc[4][2] = MFMA_BF16(af[0][0], bfv[2][0], acc[4][2]);                      \
    acc[4][2] = MFMA_BF16(af[0][1], bfv[2][1], acc[4][2]);                      \
    acc[4][3] = MFMA_BF16(af[0][0], bfv[3][0], acc[4][3]);                      \
    acc[4][3] = MFMA_BF16(af[0][1], bfv[3][1], acc[4][3]);                      \
    LG4();                                                                      \
    acc[5][2] = MFMA_BF16(af[1][0], bfv[2][0], acc[5][2]);                      \
    acc[5][2] = MFMA_BF16(af[1][1], bfv[2][1], acc[5][2]);                      \
    acc[5][3] = MFMA_BF16(af[1][0], bfv[3][0], acc[5][3]);                      \
    acc[5][3] = MFMA_BF16(af[1][1], bfv[3][1], acc[5][3]);                      \
    LG2();                                                                      \
    acc[6][2] = MFMA_BF16(af[2][0], bfv[2][0], acc[6][2]);                      \
    acc[6][2] = MFMA_BF16(af[2][1], bfv[2][1], acc[6][2]);                      \
    acc[6][3] = MFMA_BF16(af[2][0], bfv[3][0], acc[6][3]);                      \
    acc[6][3] = MFMA_BF16(af[2][1], bfv[3][1], acc[6][3]);                      \
    LG0();                                                                      \
    acc[7][2] = MFMA_BF16(af[3][0], bfv[2][0], acc[7][2]);                      \
    acc[7][2] = MFMA_BF16(af[3][1], bfv[2][1], acc[7][2]);                      \
    acc[7][3] = MFMA_BF16(af[3][0], bfv[3][0], acc[7][3]);                      \
    acc[7][3] = MFMA_BF16(af[3][1], bfv[3][1], acc[7][3]);                      \
    __builtin_amdgcn_s_setprio(0);

#define MM_0()                                                                  \
    __builtin_amdgcn_s_setprio(1);                                              \
    acc[4][0] = MFMA_BF16(af[0][0], bfv[0][0], acc[4][0]);                      \
    acc[4][0] = MFMA_BF16(af[0][1], bfv[0][1], acc[4][0]);                      \
    acc[4][1] = MFMA_BF16(af[0][0], bfv[1][0], acc[4][1]);                      \
    acc[4][1] = MFMA_BF16(af[0][1], bfv[1][1], acc[4][1]);                      \
    acc[5][0] = MFMA_BF16(af[1][0], bfv[0][0], acc[5][0]);                      \
    acc[5][0] = MFMA_BF16(af[1][1], bfv[0][1], acc[5][0]);                      \
    acc[5][1] = MFMA_BF16(af[1][0], bfv[1][0], acc[5][1]);                      \
    acc[5][1] = MFMA_BF16(af[1][1], bfv[1][1], acc[5][1]);                      \
    acc[6][0] = MFMA_BF16(af[2][0], bfv[0][0], acc[6][0]);                      \
    acc[6][0] = MFMA_BF16(af[2][1], bfv[0][1], acc[6][0]);                      \
    acc[6][1] = MFMA_BF16(af[2][0], bfv[1][0], acc[6][1]);                      \
    acc[6][1] = MFMA_BF16(af[2][1], bfv[1][1], acc[6][1]);                      \
    acc[7][0] = MFMA_BF16(af[3][0], bfv[0][0], acc[7][0]);                      \
    acc[7][0] = MFMA_BF16(af[3][1], bfv[0][1], acc[7][0]);                      \
    acc[7][1] = MFMA_BF16(af[3][0], bfv[1][0], acc[7][1]);                      \
    acc[7][1] = MFMA_BF16(af[3][1], bfv[1][1], acc[7][1]);                      \
    __builtin_amdgcn_s_setprio(0);

  const int nit = K >> 7;  // 32
#pragma unroll 1
  for (int t = 0; t < nit; ++t) {
    const int e = 2 * t, o = 2 * t + 1;
    const int e2 = (e + 2 > ktmax) ? ktmax : e + 2;
    const int o2 = (o + 2 > ktmax) ? ktmax : o + 2;
    const char* L0 = lds;
    const char* L1 = lds + 65536;
    bf16x8 af[4][2], bfv[4][2];

    PH_AB(L0); STG_HT(0, mbase, 0, 1, o); BARRIER(); MM_AB(); BARRIER();
    PH_B(L0); STG_HT(0, mbase, 1, 1, o); BARRIER(); MM_B(); BARRIER();
    PH_A(L0); STG_HT(1, nbase, 0, 0, e2); BARRIER(); MM_A(); BARRIER();
    STG_HT(1, nbase, 1, 0, e2); VM4(); BARRIER(); MM_0(); BARRIER();
    PH_AB(L1); STG_HT(0, mbase, 0, 0, e2); BARRIER(); MM_AB(); BARRIER();
    PH_B(L1); STG_HT(0, mbase, 1, 0, e2); BARRIER(); MM_B(); BARRIER();
    PH_A(L1); STG_HT(1, nbase, 0, 1, o2); BARRIER(); MM_A(); BARRIER();
    STG_HT(1, nbase, 1, 1, o2); VM4(); BARRIER(); MM_0(); BARRIER();
  }
#undef STG_HT
#undef PH_AB
#undef PH_A
#undef PH_B
#undef MM_AB
#undef MM_A
#undef MM_B
#undef MM_0
#undef BARRIER
#undef SB
#undef LG6
#undef LG4
#undef LG2
#undef LG0
#undef VM4
#undef RD
  const int crow = mbase + wm * 128 + g * 4;
  const int ccol = nbase + wn * 64 + qcol;
#pragma unroll
  for (int mi = 0; mi < 8; ++mi)
#pragma unroll
    for (int ni = 0; ni < 4; ++ni)
#pragma unroll
      for (int r = 0; r < 4; ++r)
        C[(long)(crow + mi * 16 + r) * N + (ccol + ni * 16)] = f2bf(acc[mi][ni][r]);
}

// ---------- bf16 GEMM 128^2 (m97 structure) — kept for GEMM2 (fp32 out) ----------
__global__ __launch_bounds__(256, 2) void gemm_bt(const unsigned short* __restrict__ A,
                                                  const unsigned short* __restrict__ B,
                                                  float* __restrict__ C, int N, int K) {
  __shared__ unsigned short As[128 * 32] __attribute__((aligned(16)));
  __shared__ unsigned short Bs[128 * 32] __attribute__((aligned(16)));
  const int tid = threadIdx.x;
  const int lane = tid & 63;
  const int wv = tid >> 6;
  const int wr = wv >> 1, wc = wv & 1;
  const int mbase = blockIdx.y * 128, nbase = blockIdx.x * 128;
  const int r16 = lane >> 2;
  const int k8 = (lane & 3) * 8;
  const unsigned short* Ag0 = A + (mbase + wv * 32 + r16) * K + k8;
  const unsigned short* Ag1 = Ag0 + 16 * K;
  const unsigned short* Bg0 = B + (nbase + wv * 32 + r16) * K + k8;
  const unsigned short* Bg1 = Bg0 + 16 * K;
  unsigned short* Asl = As + wv * 1024 + lane * 8;
  unsigned short* Bsl = Bs + wv * 1024 + lane * 8;
  f32x4 acc[4][4];
#pragma unroll
  for (int i = 0; i < 4; ++i)
#pragma unroll
    for (int j = 0; j < 4; ++j) { acc[i][j][0]=0.f; acc[i][j][1]=0.f; acc[i][j][2]=0.f; acc[i][j][3]=0.f; }
  const int rowA = (wr * 64 + (lane & 15)) * 32 + (lane >> 4) * 8;
  const int colB = (wc * 64 + (lane & 15)) * 32 + (lane >> 4) * 8;
  for (int kt = 0; kt < K; kt += 32) {
    gload16(Ag0 + kt, Asl);
    gload16(Ag1 + kt, Asl + 512);
    gload16(Bg0 + kt, Bsl);
    gload16(Bg1 + kt, Bsl + 512);
    __syncthreads();
    bf16x8 af[4], bfr[4];
#pragma unroll
    for (int mi = 0; mi < 4; ++mi) af[mi] = *(const bf16x8*)(As + rowA + mi * 512);
#pragma unroll
    for (int ni = 0; ni < 4; ++ni) bfr[ni] = *(const bf16x8*)(Bs + colB + ni * 512);
#pragma unroll
    for (int mi = 0; mi < 4; ++mi)
#pragma unroll
      for (int ni = 0; ni < 4; ++ni)
        acc[mi][ni] = MFMA_BF16(af[mi], bfr[ni], acc[mi][ni]);
    __syncthreads();
  }
  const int crow = mbase + wr * 64 + (lane >> 4) * 4;
  const int ccol = nbase + wc * 64 + (lane & 15);
#pragma unroll
  for (int mi = 0; mi < 4; ++mi)
#pragma unroll
    for (int ni = 0; ni < 4; ++ni)
#pragma unroll
      for (int r = 0; r < 4; ++r)
        C[(long)(crow + mi * 16 + r) * N + (ccol + ni * 16)] = acc[mi][ni][r];
}

// ---------- merged RoPE(q,k) + V-scatter (both read bf16 qkv) ----------
__global__ __launch_bounds__(256) void rope_scat(const unsigned short* __restrict__ qkv,
                                                 const int* __restrict__ pos,
                                                 unsigned short* __restrict__ Qb,
                                                 unsigned short* __restrict__ Kg,
                                                 unsigned short* __restrict__ VgT) {
  if (blockIdx.x < 10240) {
    int gw = blockIdx.x * 4 + (threadIdx.x >> 6);
    int lane = threadIdx.x & 63;
    int t = gw >> 5, h = gw & 31;
    int p = pos[t];
    int b = (t < 256) ? 0 : (t < 768) ? 1 : (t < 896) ? 2 : 3;
    float invf = exp2f(-(float)lane * 0.2076205059304601f);  // log2(10000)/64
    float ang = (float)p * invf;
    float sv = sinf(ang), cv = cosf(ang);
    const unsigned short* src = qkv + (long)t * 12288 + h * 128 + lane;
    float q1 = bf2f(src[0]), q2 = bf2f(src[64]);
    float k1 = bf2f(src[4096]), k2 = bf2f(src[4096 + 64]);
    const float scl = 0.08838834764831845f;  // 1/sqrt(128), folded into Q
    unsigned short* qd = Qb + (long)t * 4096 + h * 128 + lane;
    qd[0]  = f2bf((q1 * cv - q2 * sv) * scl);
    qd[64] = f2bf((q2 * cv + q1 * sv) * scl);
    unsigned short* kd = Kg + ((long)(b * 32 + h) * 2048 + p) * 128 + lane;
    kd[0]  = f2bf(k1 * cv - k2 * sv);
    kd[64] = f2bf(k2 * cv + k1 * sv);
    return;
  }
  int bid = blockIdx.x - 10240;        // 0..639
  int tt = bid % 20, h = bid / 20;
  int b = (tt < 4) ? 0 : (tt < 12) ? 1 : (tt < 14) ? 2 : 3;
  int q0 = (b == 0) ? 0 : (b == 1) ? 256 : (b == 2) ? 768 : 896;
  int hist = (b == 0) ? 1792 : (b == 1) ? 1024 : (b == 2) ? 1536 : 768;
  int t0 = tt * 64;
  int jb = hist + t0 - q0;
  __shared__ unsigned short vt[64][130];
  int tid = threadIdx.x;
  int jj0 = tid >> 5, c4 = (tid & 31) * 4;
#pragma unroll
  for (int ps = 0; ps < 8; ++ps) {
    int jj = jj0 + ps * 8;
    ushort4 v = *(const ushort4*)(qkv + (long)(t0 + jj) * 12288 + 8192 + h * 128 + c4);
    *(ushort4*)&vt[jj][c4] = v;
  }
  __syncthreads();
  int d = tid >> 1, half = tid & 1;
  unsigned short* dst = VgT + ((long)(b * 32 + h) * 128 + d) * 2048 + jb + half * 32;
  int j0 = half * 32;
#pragma unroll
  for (int w = 0; w < 4; ++w) {
    uint4 u;
    u.x = vt[j0 + w * 8 + 0][d] | ((unsigned)vt[j0 + w * 8 + 1][d] << 16);
    u.y = vt[j0 + w * 8 + 2][d] | ((unsigned)vt[j0 + w * 8 + 3][d] << 16);
    u.z = vt[j0 + w * 8 + 4][d] | ((unsigned)vt[j0 + w * 8 + 5][d] << 16);
    u.w = vt[j0 + w * 8 + 6][d] | ((unsigned)vt[j0 + w * 8 + 7][d] << 16);
    ((uint4*)dst)[w] = u;
  }
}

// ---------- flash attention PARTIAL over one KV chunk of 512 (QBLK=128, fp16 partials) ----------
__global__ __launch_bounds__(512) void attn_part(const unsigned short* __restrict__ Qb,
                                                 const unsigned short* __restrict__ Kg,
                                                 const unsigned short* __restrict__ VgT,
                                                 const int* __restrict__ pos,
                                                 unsigned short* __restrict__ Opart,
                                                 float* __restrict__ ml) {
  __shared__ char lds[32768] __attribute__((aligned(16)));
  int qt = blockIdx.x, h = blockIdx.y, ck = blockIdx.z;
  int tid = threadIdx.x;
  int wv = tid >> 6, lane = tid & 63;
  int b = (qt < 2) ? 0 : (qt < 6) ? 1 : (qt < 7) ? 2 : 3;
  int qb = qt * 128 + wv * 16;
  int qcol = lane & 15, g = lane >> 4;
  int t = qb + qcol;
  int p = pos[t];
  int pmax_wave = pos[qb + 15];
  int pmax_blk = pos[qt * 128 + 127];
  int kv_begin = ck * 512;
  if (kv_begin > pmax_blk) return;
  int kv_end = pmax_blk + 1;
  if (kv_end > kv_begin + 512) kv_end = kv_begin + 512;
  int nt = (kv_end - kv_begin + 31) >> 5;

  const char* KbhB = (const char*)(Kg + (long)(b * 32 + h) * 2048 * 128);
  const char* VbhB = (const char*)(VgT + (long)(b * 32 + h) * 128 * 2048);

  const int d0 = tid * 16;
  const int ksrc0 = d0 ^ (((d0 >> 8) & 7) << 4);
  const int vrow0 = d0 >> 6;
  const int vsrc0 = vrow0 * 4096 + ((d0 & 63) ^ ((vrow0 & 3) << 4));

#define STAGE(kv0, buf)                                                     \
  {                                                                          \
    const char* Ksrc = KbhB + (long)(kv0) * 256;                             \
    const char* Vsrc = VbhB + (long)(kv0) * 2;                               \
    char* Kd = lds + (buf) * 8192;                                           \
    char* Vd = lds + 16384 + (buf) * 8192;                                   \
    gload16(Ksrc + ksrc0, Kd + d0);                                          \
    gload16(Vsrc + vsrc0, Vd + d0);                                          \
  }

  const unsigned short* Qp = Qb + (long)t * 4096 + h * 128 + g * 8;
  bf16x8 qf[4];
#pragma unroll
  for (int c = 0; c < 4; ++c) qf[c] = *(const bf16x8*)(Qp + c * 32);

  const int kswz = ((qcol & 7) << 4);
  const int vswz = (g * 16) ^ ((qcol & 3) << 4);

  float m = -1e30f, lsum = 0.f;
  f32x4 o[8];
#pragma unroll
  for (int i = 0; i < 8; ++i) { o[i][0]=0.f; o[i][1]=0.f; o[i][2]=0.f; o[i][3]=0.f; }

  STAGE(kv_begin, 0);

  for (int it = 0; it < nt; ++it) {
    int cur = it & 1;
    int kv0 = kv_begin + it * 32;
    if (it + 1 < nt) {
      STAGE(kv0 + 32, cur ^ 1);
      asm volatile("s_waitcnt vmcnt(2)" ::: "memory");
    } else {
      asm volatile("s_waitcnt vmcnt(0)" ::: "memory");
    }
    __builtin_amdgcn_sched_barrier(0);
    __builtin_amdgcn_s_barrier();
    if (kv0 <= pmax_wave) {
      const char* Kc = lds + cur * 8192;
      const char* Vc = lds + 16384 + cur * 8192;
      f32x4 s0, s1;
      s0[0]=0.f;s0[1]=0.f;s0[2]=0.f;s0[3]=0.f;
      s1[0]=0.f;s1[1]=0.f;s1[2]=0.f;s1[3]=0.f;
#pragma unroll
      for (int c = 0; c < 4; ++c) {
        int colb = (g * 16 + c * 64) ^ kswz;
        bf16x8 k0 = *(const bf16x8*)(Kc + qcol * 256 + colb);
        bf16x8 k1 = *(const bf16x8*)(Kc + 4096 + qcol * 256 + colb);
        s0 = MFMA_BF16(k0, qf[c], s0);
        s1 = MFMA_BF16(k1, qf[c], s1);
      }
      int kvg = kv0 + g * 4;
      float sv[8];
#pragma unroll
      for (int r = 0; r < 4; ++r) {
        sv[r]     = (kvg + r      <= p) ? s0[r] : -1e30f;
        sv[r + 4] = (kvg + 16 + r <= p) ? s1[r] : -1e30f;
      }
      float mt = sv[0];
#pragma unroll
      for (int i = 1; i < 8; ++i) mt = fmaxf(mt, sv[i]);
      mt = fmaxf(mt, __shfl_xor(mt, 16));
      mt = fmaxf(mt, __shfl_xor(mt, 32));
      float mnew = fmaxf(m, mt);
      float corr = __expf(m - mnew);
      float ssum = 0.f;
      float pvv[8];
#pragma unroll
      for (int i = 0; i < 8; ++i) { pvv[i] = __expf(sv[i] - mnew); ssum += pvv[i]; }
      ssum += __shfl_xor(ssum, 16);
      ssum += __shfl_xor(ssum, 32);
      lsum = lsum * corr + ssum;
      m = mnew;
#pragma unroll
      for (int df = 0; df < 8; ++df) o[df] *= corr;
      unsigned pk0 = (unsigned)f2bf(pvv[0]) | ((unsigned)f2bf(pvv[1]) << 16);
      unsigned pk1 = (unsigned)f2bf(pvv[2]) | ((unsigned)f2bf(pvv[3]) << 16);
      unsigned pk2 = (unsigned)f2bf(pvv[4]) | ((unsigned)f2bf(pvv[5]) << 16);
      unsigned pk3 = (unsigned)f2bf(pvv[6]) | ((unsigned)f2bf(pvv[7]) << 16);
      int s0l = ((g & 1) * 32) + qcol;
      int s1l = s0l + 16;
      unsigned a0 = (unsigned)__shfl((int)pk0, s0l), a1 = (unsigned)__shfl((int)pk1, s0l);
      unsigned a2 = (unsigned)__shfl((int)pk2, s0l), a3 = (unsigned)__shfl((int)pk3, s0l);
      unsigned b0 = (unsigned)__shfl((int)pk0, s1l), b1 = (unsigned)__shfl((int)pk1, s1l);
      unsigned b2 = (unsigned)__shfl((int)pk2, s1l), b3 = (unsigned)__shfl((int)pk3, s1l);
      bool hi = (g >= 2);
      u32x4 wv4;
      wv4[0] = hi ? a2 : a0; wv4[1] = hi ? a3 : a1;
      wv4[2] = hi ? b2 : b0; wv4[3] = hi ? b3 : b1;
      bf16x8 pfrag = __builtin_bit_cast(bf16x8, wv4);
#pragma unroll
      for (int df = 0; df < 8; ++df) {
        bf16x8 vf = *(const bf16x8*)(Vc + (df * 16 + qcol) * 64 + vswz);
        o[df] = MFMA_BF16(vf, pfrag, o[df]);
      }
    }
    __builtin_amdgcn_s_barrier();
  }
#undef STAGE
  // write unnormalized partial O (fp16) and (m, l) fp32
  long pbase = (long)((qt * 32 + h) * 4 + ck);
  unsigned short* Op = Opart + pbase * 16384 + (wv * 16 + qcol) * 128 + g * 4;
#pragma unroll
  for (int df = 0; df < 8; ++df) {
    ushort4 hv;
    hv.x = f2h(o[df][0]); hv.y = f2h(o[df][1]);
    hv.z = f2h(o[df][2]); hv.w = f2h(o[df][3]);
    *(ushort4*)(Op + df * 16) = hv;
  }
  if (g == 0) {
    float* mlp = ml + pbase * 256 + (wv * 16 + qcol) * 2;
    mlp[0] = m;
    mlp[1] = lsum;
  }
}

// ---------- combine partials across KV chunks (fp16 partials in) ----------
__global__ __launch_bounds__(256) void attn_comb(const unsigned short* __restrict__ Opart,
                                                 const float* __restrict__ ml,
                                                 const int* __restrict__ pos,
                                                 unsigned short* __restrict__ Ao) {
  int qt = blockIdx.x, h = blockIdx.y;   // qt over 64-row tiles (0..19)
  int tid = threadIdx.x;
  int q = tid >> 2, dq = (tid & 3) * 32;
  int t = qt * 64 + q;
  int p = pos[t];
  int ncv = (p >> 9) + 1;
  if (ncv > 4) ncv = 4;
  int bigqt = qt >> 1;
  int row = (qt & 1) * 64 + q;           // row within 128-row partial
  long base = (long)(bigqt * 32 + h) * 4;
  float M = -1e30f;
#pragma unroll
  for (int c = 0; c < 4; ++c)
    if (c < ncv) M = fmaxf(M, ml[(base + c) * 256 + row * 2]);
  float L = 0.f;
#pragma unroll
  for (int c = 0; c < 4; ++c)
    if (c < ncv) L += __expf(ml[(base + c) * 256 + row * 2] - M) * ml[(base + c) * 256 + row * 2 + 1];
  f32x4 acc[8];
#pragma unroll
  for (int i = 0; i < 8; ++i) { acc[i][0]=0.f; acc[i][1]=0.f; acc[i][2]=0.f; acc[i][3]=0.f; }
#pragma unroll
  for (int c = 0; c < 4; ++c)
    if (c < ncv) {
      float wc = __expf(ml[(base + c) * 256 + row * 2] - M);
      const ushort4* src = (const ushort4*)(Opart + (base + c) * 16384 + row * 128 + dq);
#pragma unroll
      for (int i = 0; i < 8; ++i) {
        ushort4 s = src[i];
        acc[i][0] += wc * h2f(s.x); acc[i][1] += wc * h2f(s.y);
        acc[i][2] += wc * h2f(s.z); acc[i][3] += wc * h2f(s.w);
      }
    }
  float inv = 1.f / L;
  unsigned short* dst = Ao + (long)t * 4096 + h * 128 + dq;
#pragma unroll
  for (int i = 0; i < 8; ++i) {
    ushort4 ov;
    ov.x = f2bf(acc[i][0] * inv); ov.y = f2bf(acc[i][1] * inv);
    ov.z = f2bf(acc[i][2] * inv); ov.w = f2bf(acc[i][3] * inv);
    *(ushort4*)(dst + i * 4) = ov;
  }
}

// ---------- launch ----------
extern "C" void kernel_launch(void* const* d_in, const int* in_sizes, int n_in,
                              void* d_out, int out_size, void* d_ws, size_t ws_size,
                              hipStream_t stream) {
  const float* hs   = (const float*)d_in[0];
  const float* wq   = (const float*)d_in[1];
  const float* wk   = (const float*)d_in[2];
  const float* wvp  = (const float*)d_in[3];
  const float* wo   = (const float*)d_in[4];
  const float* pkey = (const float*)d_in[5];
  const float* pval = (const float*)d_in[6];
  const int* pos    = (const int*)d_in[7];
  const int* btab   = (const int*)d_in[8];

  unsigned short* Wqkv = (unsigned short*)d_ws;                       // [12288][4096] bf16
  unsigned short* Wo   = Wqkv + (size_t)12288 * 4096;                 // [4096][4096]
  unsigned short* Hb   = Wo + (size_t)4096 * 4096;                    // [1280][4096]
  unsigned short* qkvb = Hb + (size_t)1280 * 4096;                    // [1280][12288] bf16
  unsigned short* Qbf  = qkvb + (size_t)1280 * 12288 * 2;             // (region kept same size as old fp32)
  unsigned short* Kg   = Qbf + (size_t)1280 * 4096;                   // [4][32][2048][128]
  unsigned short* VgT  = Kg + (size_t)4 * 32 * 2048 * 128;            // [4][32][128][2048]
  unsigned short* Aob  = VgT + (size_t)4 * 32 * 2048 * 128;           // [1280][4096]
  unsigned short* Opart = (unsigned short*)d_ws;                      // overlay Wqkv (dead after gemm1): 41.9MB fp16
  float* mlb   = (float*)((char*)d_ws + 83886080);                    // +1.31MB < 100.7MB
  if (ws_size < 362807296ull) return;

  cvt_gather<<<37888, 256, 0, stream>>>(wq, wk, wvp, wo, hs, Wqkv, pkey, pval, btab, Kg, VgT);

  gemm256<<<dim3(48, 5), 512, 131072, stream>>>(Hb, Wqkv, qkvb, 12288, 4096);
  rope_scat<<<10880, 256, 0, stream>>>(qkvb, pos, Qbf, Kg, VgT);
  attn_part<<<dim3(10, 32, 4), 512, 0, stream>>>(Qbf, Kg, VgT, pos, Opart, mlb);
  attn_comb<<<dim3(20, 32), 256, 0, stream>>>(Opart, mlb, pos, Aob);
  gemm_bt<<<dim3(32, 10), 256, 0, stream>>>(Aob, Wo, (float*)d_out, 4096, 4096);
}